// Round 1
// baseline (409.141 us; speedup 1.0000x reference)
//
#include <hip/hip_runtime.h>
#include <stdint.h>

typedef __attribute__((ext_vector_type(8))) __bf16 bf16x8;
typedef __attribute__((ext_vector_type(4))) float f32x4;
typedef __attribute__((ext_vector_type(8))) unsigned short ushort8;
typedef __attribute__((ext_vector_type(4))) unsigned short ushort4v;
typedef unsigned short u16;

__device__ __forceinline__ u16 f2bf(float f) {
    __bf16 h = (__bf16)f;
    return __builtin_bit_cast(u16, h);
}

__device__ __forceinline__ f32x4 mfma16(bf16x8 a, bf16x8 b, f32x4 c) {
    return __builtin_amdgcn_mfma_f32_16x16x32_bf16(a, b, c, 0, 0, 0);
}

// ---------------------------------------------------------------------------
// Weight prep: WT[j][k] = W_sel[k][j%256] as bf16 (j<256:Wq, <512:Wk, <768:Wv)
//              WOT[o][h] = Wo[h][o] as bf16
// ---------------------------------------------------------------------------
__global__ __launch_bounds__(256) void prep_w(
    const float* __restrict__ Wq, const float* __restrict__ Wk,
    const float* __restrict__ Wv, const float* __restrict__ Wo,
    u16* __restrict__ WT, u16* __restrict__ WOT)
{
    int idx = blockIdx.x * 256 + threadIdx.x;  // 0..262143
    if (idx < 196608) {
        int j = idx >> 8, k = idx & 255;
        const float* W = (j < 256) ? Wq : (j < 512) ? Wk : Wv;
        WT[idx] = f2bf(W[k * 256 + (j & 255)]);
    } else {
        int t = idx - 196608;
        int j = t >> 8, k = t & 255;
        WOT[t] = f2bf(Wo[k * 256 + j]);
    }
}

// ---------------------------------------------------------------------------
// QKV projection: C[65536,768] = relu(X[65536,256] @ W + b), bf16 out.
// Full K (256) of the A-panel staged once in LDS; 6 col-blocks of 128.
// V written transposed: vt[b][h][n].
// ---------------------------------------------------------------------------
__global__ __launch_bounds__(256, 2) void qkv_gemm(
    const float* __restrict__ X, const u16* __restrict__ WT,
    const float* __restrict__ bQ, const float* __restrict__ bK,
    const float* __restrict__ bV,
    u16* __restrict__ outQ, u16* __restrict__ outK, u16* __restrict__ outVT)
{
    __shared__ __align__(16) u16 As[128 * 256];  // 64KB, XOR-swizzled rows
    __shared__ __align__(16) u16 Bs[128 * 64];   // 16KB, XOR-swizzled rows
    const int tid = threadIdx.x;
    const int m0 = blockIdx.x * 128;

    // Stage A panel (f32 -> bf16), coalesced float4 loads.
    #pragma unroll
    for (int i = 0; i < 32; ++i) {
        int flat = (i * 256 + tid) * 4;
        int r = flat >> 8, c = flat & 255;
        const float4 f = *reinterpret_cast<const float4*>(X + (size_t)(m0 + r) * 256 + c);
        ushort4v h;
        h.x = f2bf(f.x); h.y = f2bf(f.y); h.z = f2bf(f.z); h.w = f2bf(f.w);
        int byte = (r * 512 + c * 2) ^ ((r & 7) << 4);
        *reinterpret_cast<ushort4v*>(reinterpret_cast<char*>(As) + byte) = h;
    }

    const int lane = tid & 63, wid = tid >> 6;
    const int wr = wid >> 1, wc = wid & 1;
    const int lr = lane & 15, lg = lane >> 4;

    for (int cb = 0; cb < 6; ++cb) {
        const int jbase = cb * 128;
        f32x4 acc[4][4];
        #pragma unroll
        for (int a = 0; a < 4; ++a)
            #pragma unroll
            for (int b = 0; b < 4; ++b) acc[a][b] = (f32x4){0.f, 0.f, 0.f, 0.f};

        for (int kk = 0; kk < 256; kk += 64) {
            __syncthreads();  // protect Bs against previous readers
            #pragma unroll
            for (int i = 0; i < 4; ++i) {
                int e = (i * 256 + tid) * 8;
                int r = e >> 6, c = e & 63;
                ushort8 d = *reinterpret_cast<const ushort8*>(WT + (size_t)(jbase + r) * 256 + kk + c);
                int byte = (r * 128 + c * 2) ^ ((r & 7) << 4);
                *reinterpret_cast<ushort8*>(reinterpret_cast<char*>(Bs) + byte) = d;
            }
            __syncthreads();
            #pragma unroll
            for (int ks = 0; ks < 2; ++ks) {
                bf16x8 af[4], bfr[4];
                #pragma unroll
                for (int mt = 0; mt < 4; ++mt) {
                    int r = wr * 64 + mt * 16 + lr;
                    int byte = (r * 512 + (kk + ks * 32 + lg * 8) * 2) ^ ((r & 7) << 4);
                    af[mt] = *reinterpret_cast<const bf16x8*>(reinterpret_cast<const char*>(As) + byte);
                }
                #pragma unroll
                for (int nt = 0; nt < 4; ++nt) {
                    int r = wc * 64 + nt * 16 + lr;
                    int byte = (r * 128 + (ks * 32 + lg * 8) * 2) ^ ((r & 7) << 4);
                    bfr[nt] = *reinterpret_cast<const bf16x8*>(reinterpret_cast<const char*>(Bs) + byte);
                }
                #pragma unroll
                for (int mt = 0; mt < 4; ++mt)
                    #pragma unroll
                    for (int nt = 0; nt < 4; ++nt)
                        acc[mt][nt] = mfma16(af[mt], bfr[nt], acc[mt][nt]);
            }
        }
        // Epilogue: bias + relu + bf16 store.
        const float* bias = (cb < 2) ? bQ : (cb < 4) ? bK : bV;
        float bcol[4];
        #pragma unroll
        for (int nt = 0; nt < 4; ++nt)
            bcol[nt] = bias[(jbase + wc * 64 + nt * 16 + lr) & 255];
        #pragma unroll
        for (int mt = 0; mt < 4; ++mt) {
            #pragma unroll
            for (int nt = 0; nt < 4; ++nt) {
                #pragma unroll
                for (int j = 0; j < 4; ++j) {
                    float v = fmaxf(acc[mt][nt][j] + bcol[nt], 0.f);
                    u16 h = f2bf(v);
                    int row = m0 + wr * 64 + mt * 16 + lg * 4 + j;  // global (b*512+n)
                    int col = jbase + wc * 64 + nt * 16 + lr;       // 0..767
                    if (cb < 2) {
                        outQ[(size_t)row * 256 + col] = h;
                    } else if (cb < 4) {
                        outK[(size_t)row * 256 + (col - 256)] = h;
                    } else {
                        int bb = row >> 9, n = row & 511;
                        outVT[(size_t)bb * 131072 + (size_t)(col - 512) * 512 + n] = h;
                    }
                }
            }
        }
    }
}

// ---------------------------------------------------------------------------
// Flash attention: per block = one batch x 64 q-rows (4 waves x 16 rows).
// Q in registers; K,V tiles in swizzled LDS; online softmax; exact
// s*m - 9e15*(1-m) mask semantics. Output bf16 (over Q buffer).
// ---------------------------------------------------------------------------
__global__ __launch_bounds__(256, 2) void attn_kernel(
    const u16* __restrict__ Q, const u16* __restrict__ K,
    const u16* __restrict__ VT, const float* __restrict__ Mask,
    u16* __restrict__ Out)
{
    __shared__ __align__(16) u16 k_lds[64 * 256];   // 32KB [key][h]
    __shared__ __align__(16) u16 v_lds[256 * 64];   // 32KB [h][key]
    __shared__ __align__(16) u16 p_lds[4][16 * 64]; // 8KB per-wave P
    const int tid = threadIdx.x;
    const int b  = blockIdx.x & 127;   // batch-major => same XCD per batch
    const int rb = blockIdx.x >> 7;
    const int lane = tid & 63, wid = tid >> 6;
    const int lr = lane & 15, lg = lane >> 4;
    const int n0 = rb * 64 + wid * 16;
    const u16* qbat = Q  + (size_t)b * 512 * 256;
    const u16* kbat = K  + (size_t)b * 512 * 256;
    const u16* vbat = VT + (size_t)b * 256 * 512;

    // Q fragments: rows n0+lr, all K=256 (8 chunks of 32).
    bf16x8 qf[8];
    #pragma unroll
    for (int ks = 0; ks < 8; ++ks)
        qf[ks] = *reinterpret_cast<const bf16x8*>(qbat + (size_t)(n0 + lr) * 256 + ks * 32 + lg * 8);

    f32x4 acc[16];
    #pragma unroll
    for (int i = 0; i < 16; ++i) acc[i] = (f32x4){0.f, 0.f, 0.f, 0.f};
    float mreg[4], lreg[4];
    #pragma unroll
    for (int j = 0; j < 4; ++j) { mreg[j] = -__builtin_inff(); lreg[j] = 0.f; }

    for (int kt = 0; kt < 8; ++kt) {
        __syncthreads();
        #pragma unroll
        for (int i = 0; i < 8; ++i) {  // stage K tile [64][256]
            int e = (i * 256 + tid) * 8;
            int kr = e >> 8, c = e & 255;
            ushort8 d = *reinterpret_cast<const ushort8*>(kbat + (size_t)(kt * 64 + kr) * 256 + c);
            int byte = (kr * 512 + c * 2) ^ ((kr & 7) << 4);
            *reinterpret_cast<ushort8*>(reinterpret_cast<char*>(k_lds) + byte) = d;
        }
        #pragma unroll
        for (int i = 0; i < 8; ++i) {  // stage V tile [256][64]
            int e = (i * 256 + tid) * 8;
            int hr = e >> 6, c = e & 63;
            ushort8 d = *reinterpret_cast<const ushort8*>(vbat + (size_t)hr * 512 + kt * 64 + c);
            int byte = (hr * 128 + c * 2) ^ ((hr & 7) << 4);
            *reinterpret_cast<ushort8*>(reinterpret_cast<char*>(v_lds) + byte) = d;
        }
        __syncthreads();

        // S = Q K^T : 16 rows x 64 keys per wave
        f32x4 s[4];
        #pragma unroll
        for (int ct = 0; ct < 4; ++ct) s[ct] = (f32x4){0.f, 0.f, 0.f, 0.f};
        #pragma unroll
        for (int ks = 0; ks < 8; ++ks) {
            #pragma unroll
            for (int ct = 0; ct < 4; ++ct) {
                int kr = ct * 16 + lr;
                int byte = (kr * 512 + (ks * 32 + lg * 8) * 2) ^ ((kr & 7) << 4);
                bf16x8 kf = *reinterpret_cast<const bf16x8*>(reinterpret_cast<const char*>(k_lds) + byte);
                s[ct] = mfma16(qf[ks], kf, s[ct]);
            }
        }

        // mask + online softmax
        float p[4][4];
        #pragma unroll
        for (int ct = 0; ct < 4; ++ct) {
            #pragma unroll
            for (int j = 0; j < 4; ++j) {
                int qn = n0 + lg * 4 + j;
                int key = kt * 64 + ct * 16 + lr;
                float msk = Mask[((size_t)b * 512 + qn) * 512 + key];
                p[ct][j] = s[ct][j] * msk - 9.0e15f * (1.0f - msk);
            }
        }
        float scalef[4];
        #pragma unroll
        for (int j = 0; j < 4; ++j) {
            float r0 = fmaxf(fmaxf(p[0][j], p[1][j]), fmaxf(p[2][j], p[3][j]));
            r0 = fmaxf(r0, __shfl_xor(r0, 1));
            r0 = fmaxf(r0, __shfl_xor(r0, 2));
            r0 = fmaxf(r0, __shfl_xor(r0, 4));
            r0 = fmaxf(r0, __shfl_xor(r0, 8));
            float mnew = fmaxf(mreg[j], r0);
            scalef[j] = __expf(mreg[j] - mnew);  // first iter: exp(-inf)=0, l=0 anyway
            mreg[j] = mnew;
            float psum = 0.f;
            #pragma unroll
            for (int ct = 0; ct < 4; ++ct) {
                float e = __expf(p[ct][j] - mnew);
                p[ct][j] = e;
                psum += e;
            }
            lreg[j] = lreg[j] * scalef[j] + psum;
        }
        #pragma unroll
        for (int ht = 0; ht < 16; ++ht)
            #pragma unroll
            for (int j = 0; j < 4; ++j) acc[ht][j] *= scalef[j];

        // P (D-layout) -> per-wave LDS -> A-fragment layout
        #pragma unroll
        for (int ct = 0; ct < 4; ++ct) {
            #pragma unroll
            for (int j = 0; j < 4; ++j) {
                int pr = lg * 4 + j, pc = ct * 16 + lr;
                int byte = (pr * 128 + pc * 2) ^ ((pr & 7) << 4);
                *reinterpret_cast<u16*>(reinterpret_cast<char*>(p_lds[wid]) + byte) = f2bf(p[ct][j]);
            }
        }
        // PV: out[16 rows][256 h] += P[16][64] @ V[64][256]
        #pragma unroll
        for (int ks2 = 0; ks2 < 2; ++ks2) {
            int byteA = (lr * 128 + (ks2 * 32 + lg * 8) * 2) ^ ((lr & 7) << 4);
            bf16x8 pf = *reinterpret_cast<const bf16x8*>(reinterpret_cast<const char*>(p_lds[wid]) + byteA);
            #pragma unroll
            for (int ht = 0; ht < 16; ++ht) {
                int hrow = ht * 16 + lr;
                int byteB = (hrow * 128 + (ks2 * 32 + lg * 8) * 2) ^ ((hrow & 7) << 4);
                bf16x8 vf = *reinterpret_cast<const bf16x8*>(reinterpret_cast<const char*>(v_lds) + byteB);
                acc[ht] = mfma16(pf, vf, acc[ht]);
            }
        }
    }

    // finalize: normalize and store bf16
    #pragma unroll
    for (int j = 0; j < 4; ++j) {
        float lt = lreg[j];
        lt += __shfl_xor(lt, 1);
        lt += __shfl_xor(lt, 2);
        lt += __shfl_xor(lt, 4);
        lt += __shfl_xor(lt, 8);
        float inv = 1.0f / lt;
        int qn = n0 + lg * 4 + j;
        u16* orow = Out + ((size_t)b * 512 + qn) * 256;
        #pragma unroll
        for (int ht = 0; ht < 16; ++ht)
            orow[ht * 16 + lr] = f2bf(acc[ht][j] * inv);
    }
}

// ---------------------------------------------------------------------------
// Output projection: Out[65536,256] = relu(A[65536,256](bf16) @ Wo + bo), f32.
// ---------------------------------------------------------------------------
__global__ __launch_bounds__(256, 2) void out_gemm(
    const u16* __restrict__ A, const u16* __restrict__ WOT,
    const float* __restrict__ bO, float* __restrict__ Out)
{
    __shared__ __align__(16) u16 As[128 * 256];
    __shared__ __align__(16) u16 Bs[128 * 64];
    const int tid = threadIdx.x;
    const int m0 = blockIdx.x * 128;

    #pragma unroll
    for (int i = 0; i < 16; ++i) {
        int e = (i * 256 + tid) * 8;
        int r = e >> 8, c = e & 255;
        ushort8 d = *reinterpret_cast<const ushort8*>(A + (size_t)(m0 + r) * 256 + c);
        int byte = (r * 512 + c * 2) ^ ((r & 7) << 4);
        *reinterpret_cast<ushort8*>(reinterpret_cast<char*>(As) + byte) = d;
    }

    const int lane = tid & 63, wid = tid >> 6;
    const int wr = wid >> 1, wc = wid & 1;
    const int lr = lane & 15, lg = lane >> 4;

    for (int cb = 0; cb < 2; ++cb) {
        const int jbase = cb * 128;
        f32x4 acc[4][4];
        #pragma unroll
        for (int a = 0; a < 4; ++a)
            #pragma unroll
            for (int b = 0; b < 4; ++b) acc[a][b] = (f32x4){0.f, 0.f, 0.f, 0.f};

        for (int kk = 0; kk < 256; kk += 64) {
            __syncthreads();
            #pragma unroll
            for (int i = 0; i < 4; ++i) {
                int e = (i * 256 + tid) * 8;
                int r = e >> 6, c = e & 63;
                ushort8 d = *reinterpret_cast<const ushort8*>(WOT + (size_t)(jbase + r) * 256 + kk + c);
                int byte = (r * 128 + c * 2) ^ ((r & 7) << 4);
                *reinterpret_cast<ushort8*>(reinterpret_cast<char*>(Bs) + byte) = d;
            }
            __syncthreads();
            #pragma unroll
            for (int ks = 0; ks < 2; ++ks) {
                bf16x8 af[4], bfr[4];
                #pragma unroll
                for (int mt = 0; mt < 4; ++mt) {
                    int r = wr * 64 + mt * 16 + lr;
                    int byte = (r * 512 + (kk + ks * 32 + lg * 8) * 2) ^ ((r & 7) << 4);
                    af[mt] = *reinterpret_cast<const bf16x8*>(reinterpret_cast<const char*>(As) + byte);
                }
                #pragma unroll
                for (int nt = 0; nt < 4; ++nt) {
                    int r = wc * 64 + nt * 16 + lr;
                    int byte = (r * 128 + (ks * 32 + lg * 8) * 2) ^ ((r & 7) << 4);
                    bfr[nt] = *reinterpret_cast<const bf16x8*>(reinterpret_cast<const char*>(Bs) + byte);
                }
                #pragma unroll
                for (int mt = 0; mt < 4; ++mt)
                    #pragma unroll
                    for (int nt = 0; nt < 4; ++nt)
                        acc[mt][nt] = mfma16(af[mt], bfr[nt], acc[mt][nt]);
            }
        }
        float bcol[4];
        #pragma unroll
        for (int nt = 0; nt < 4; ++nt)
            bcol[nt] = bO[jbase + wc * 64 + nt * 16 + lr];
        #pragma unroll
        for (int mt = 0; mt < 4; ++mt) {
            #pragma unroll
            for (int nt = 0; nt < 4; ++nt) {
                #pragma unroll
                for (int j = 0; j < 4; ++j) {
                    float v = fmaxf(acc[mt][nt][j] + bcol[nt], 0.f);
                    int row = m0 + wr * 64 + mt * 16 + lg * 4 + j;
                    int col = jbase + wc * 64 + nt * 16 + lr;
                    Out[(size_t)row * 256 + col] = v;
                }
            }
        }
    }
}

// ---------------------------------------------------------------------------
extern "C" void kernel_launch(void* const* d_in, const int* in_sizes, int n_in,
                              void* d_out, int out_size, void* d_ws, size_t ws_size,
                              hipStream_t stream) {
    const float* x    = (const float*)d_in[0];
    const float* mask = (const float*)d_in[1];
    const float* Wv   = (const float*)d_in[2];
    const float* bv   = (const float*)d_in[3];
    const float* Wk   = (const float*)d_in[4];
    const float* bk   = (const float*)d_in[5];
    const float* Wq   = (const float*)d_in[6];
    const float* bq   = (const float*)d_in[7];
    const float* Wo   = (const float*)d_in[8];
    const float* bo   = (const float*)d_in[9];
    float* out = (float*)d_out;

    char* ws = (char*)d_ws;
    u16* WT  = (u16*)(ws);                          // 768*256 bf16 = 384KB
    u16* WOT = (u16*)(ws + 393216);                 // 256*256 bf16 = 128KB
    u16* Qb  = (u16*)(ws + 524288);                 // 33.55MB (also attn out)
    u16* Kb  = (u16*)(ws + 524288 + 33554432);      // 33.55MB
    u16* VTb = (u16*)(ws + 524288 + 2 * 33554432);  // 33.55MB, [b][h][n]

    prep_w<<<1024, 256, 0, stream>>>(Wq, Wk, Wv, Wo, WT, WOT);
    qkv_gemm<<<512, 256, 0, stream>>>(x, WT, bq, bk, bv, Qb, Kb, VTb);
    attn_kernel<<<1024, 256, 0, stream>>>(Qb, Kb, VTb, mask, Qb);
    out_gemm<<<512, 256, 0, stream>>>(Qb, WOT, bo, out);
}

// Round 2
// 380.308 us; speedup vs baseline: 1.0758x; 1.0758x over previous
//
#include <hip/hip_runtime.h>
#include <stdint.h>

typedef __attribute__((ext_vector_type(8))) __bf16 bf16x8;
typedef __attribute__((ext_vector_type(4))) float f32x4;
typedef __attribute__((ext_vector_type(8))) unsigned short ushort8;
typedef __attribute__((ext_vector_type(4))) unsigned short ushort4v;
typedef unsigned short u16;

__device__ __forceinline__ u16 f2bf(float f) {
    __bf16 h = (__bf16)f;
    return __builtin_bit_cast(u16, h);
}

__device__ __forceinline__ f32x4 mfma16(bf16x8 a, bf16x8 b, f32x4 c) {
    return __builtin_amdgcn_mfma_f32_16x16x32_bf16(a, b, c, 0, 0, 0);
}

// ---------------------------------------------------------------------------
// Weight prep: WT[j][k] = W_sel[k][j%256] as bf16 (j<256:Wq, <512:Wk, <768:Wv)
//              WOT[o][h] = Wo[h][o] as bf16
// ---------------------------------------------------------------------------
__global__ __launch_bounds__(256) void prep_w(
    const float* __restrict__ Wq, const float* __restrict__ Wk,
    const float* __restrict__ Wv, const float* __restrict__ Wo,
    u16* __restrict__ WT, u16* __restrict__ WOT)
{
    int idx = blockIdx.x * 256 + threadIdx.x;  // 0..262143
    if (idx < 196608) {
        int j = idx >> 8, k = idx & 255;
        const float* W = (j < 256) ? Wq : (j < 512) ? Wk : Wv;
        WT[idx] = f2bf(W[k * 256 + (j & 255)]);
    } else {
        int t = idx - 196608;
        int j = t >> 8, k = t & 255;
        WOT[t] = f2bf(Wo[k * 256 + j]);
    }
}

// ---------------------------------------------------------------------------
// QKV projection: C[65536,768] = relu(X[65536,256] @ W + b), bf16 out.
// Full K (256) of the A-panel staged once in LDS; 6 col-blocks of 128.
// V written transposed: vt[b][h][n].
// ---------------------------------------------------------------------------
__global__ __launch_bounds__(256, 2) void qkv_gemm(
    const float* __restrict__ X, const u16* __restrict__ WT,
    const float* __restrict__ bQ, const float* __restrict__ bK,
    const float* __restrict__ bV,
    u16* __restrict__ outQ, u16* __restrict__ outK, u16* __restrict__ outVT)
{
    __shared__ __align__(16) u16 As[128 * 256];  // 64KB, XOR-swizzled rows
    __shared__ __align__(16) u16 Bs[128 * 64];   // 16KB, XOR-swizzled rows
    const int tid = threadIdx.x;
    const int m0 = blockIdx.x * 128;

    // Stage A panel (f32 -> bf16), coalesced float4 loads.
    #pragma unroll
    for (int i = 0; i < 32; ++i) {
        int flat = (i * 256 + tid) * 4;
        int r = flat >> 8, c = flat & 255;
        const float4 f = *reinterpret_cast<const float4*>(X + (size_t)(m0 + r) * 256 + c);
        ushort4v h;
        h.x = f2bf(f.x); h.y = f2bf(f.y); h.z = f2bf(f.z); h.w = f2bf(f.w);
        int byte = (r * 512 + c * 2) ^ ((r & 7) << 4);
        *reinterpret_cast<ushort4v*>(reinterpret_cast<char*>(As) + byte) = h;
    }

    const int lane = tid & 63, wid = tid >> 6;
    const int wr = wid >> 1, wc = wid & 1;
    const int lr = lane & 15, lg = lane >> 4;

    for (int cb = 0; cb < 6; ++cb) {
        const int jbase = cb * 128;
        f32x4 acc[4][4];
        #pragma unroll
        for (int a = 0; a < 4; ++a)
            #pragma unroll
            for (int b = 0; b < 4; ++b) acc[a][b] = (f32x4){0.f, 0.f, 0.f, 0.f};

        for (int kk = 0; kk < 256; kk += 64) {
            __syncthreads();  // protect Bs against previous readers
            #pragma unroll
            for (int i = 0; i < 4; ++i) {
                int e = (i * 256 + tid) * 8;
                int r = e >> 6, c = e & 63;
                ushort8 d = *reinterpret_cast<const ushort8*>(WT + (size_t)(jbase + r) * 256 + kk + c);
                int byte = (r * 128 + c * 2) ^ ((r & 7) << 4);
                *reinterpret_cast<ushort8*>(reinterpret_cast<char*>(Bs) + byte) = d;
            }
            __syncthreads();
            #pragma unroll
            for (int ks = 0; ks < 2; ++ks) {
                bf16x8 af[4], bfr[4];
                #pragma unroll
                for (int mt = 0; mt < 4; ++mt) {
                    int r = wr * 64 + mt * 16 + lr;
                    int byte = (r * 512 + (kk + ks * 32 + lg * 8) * 2) ^ ((r & 7) << 4);
                    af[mt] = *reinterpret_cast<const bf16x8*>(reinterpret_cast<const char*>(As) + byte);
                }
                #pragma unroll
                for (int nt = 0; nt < 4; ++nt) {
                    int r = wc * 64 + nt * 16 + lr;
                    int byte = (r * 128 + (ks * 32 + lg * 8) * 2) ^ ((r & 7) << 4);
                    bfr[nt] = *reinterpret_cast<const bf16x8*>(reinterpret_cast<const char*>(Bs) + byte);
                }
                #pragma unroll
                for (int mt = 0; mt < 4; ++mt)
                    #pragma unroll
                    for (int nt = 0; nt < 4; ++nt)
                        acc[mt][nt] = mfma16(af[mt], bfr[nt], acc[mt][nt]);
            }
        }
        // Epilogue: bias + relu + bf16 store.
        const float* bias = (cb < 2) ? bQ : (cb < 4) ? bK : bV;
        float bcol[4];
        #pragma unroll
        for (int nt = 0; nt < 4; ++nt)
            bcol[nt] = bias[(jbase + wc * 64 + nt * 16 + lr) & 255];
        #pragma unroll
        for (int mt = 0; mt < 4; ++mt) {
            #pragma unroll
            for (int nt = 0; nt < 4; ++nt) {
                #pragma unroll
                for (int j = 0; j < 4; ++j) {
                    float v = fmaxf(acc[mt][nt][j] + bcol[nt], 0.f);
                    u16 h = f2bf(v);
                    int row = m0 + wr * 64 + mt * 16 + lg * 4 + j;  // global (b*512+n)
                    int col = jbase + wc * 64 + nt * 16 + lr;       // 0..767
                    if (cb < 2) {
                        outQ[(size_t)row * 256 + col] = h;
                    } else if (cb < 4) {
                        outK[(size_t)row * 256 + (col - 256)] = h;
                    } else {
                        int bb = row >> 9, n = row & 511;
                        outVT[(size_t)bb * 131072 + (size_t)(col - 512) * 512 + n] = h;
                    }
                }
            }
        }
    }
}

// ---------------------------------------------------------------------------
// Flash attention, barrier-free: per block = one batch x 64 q-rows, 4 fully
// independent waves x 16 rows. K/V fragments read directly from global
// (L2-resident: all 8 row-blocks of a batch land on the same XCD since
// 128 % 8 == 0). Only per-wave P-shuffle LDS remains (8KB). Mask loads
// hoisted to loop top + nontemporal (one-shot 128MB stream, don't pollute L2).
// ---------------------------------------------------------------------------
__global__ __launch_bounds__(256) void attn_kernel(
    const u16* __restrict__ Q, const u16* __restrict__ K,
    const u16* __restrict__ VT, const float* __restrict__ Mask,
    u16* __restrict__ Out)
{
    __shared__ __align__(16) u16 p_lds[4][16 * 64]; // 8KB total, per-wave
    const int tid = threadIdx.x;
    const int b  = blockIdx.x & 127;   // batch; same XCD for all rb of a batch
    const int rb = blockIdx.x >> 7;
    const int lane = tid & 63, wid = tid >> 6;
    const int lr = lane & 15, lg = lane >> 4;
    const int n0 = rb * 64 + wid * 16;
    const u16* qbat = Q  + (size_t)b * 512 * 256;
    const u16* kbat = K  + (size_t)b * 512 * 256;
    const u16* vbat = VT + (size_t)b * 256 * 512;
    const float* mbat = Mask + ((size_t)b * 512 + n0 + lg * 4) * 512;

    // Q fragments: rows n0+lr, all K=256 (8 chunks of 32).
    bf16x8 qf[8];
    #pragma unroll
    for (int ks = 0; ks < 8; ++ks)
        qf[ks] = *reinterpret_cast<const bf16x8*>(qbat + (size_t)(n0 + lr) * 256 + ks * 32 + lg * 8);

    f32x4 acc[16];
    #pragma unroll
    for (int i = 0; i < 16; ++i) acc[i] = (f32x4){0.f, 0.f, 0.f, 0.f};
    float mreg[4], lreg[4];
    #pragma unroll
    for (int j = 0; j < 4; ++j) { mreg[j] = -__builtin_inff(); lreg[j] = 0.f; }

    for (int kt = 0; kt < 8; ++kt) {
        // ---- mask loads first (independent of QK^T; overlap with MFMA) ----
        float msk[4][4];
        #pragma unroll
        for (int ct = 0; ct < 4; ++ct) {
            #pragma unroll
            for (int j = 0; j < 4; ++j) {
                int key = kt * 64 + ct * 16 + lr;
                msk[ct][j] = __builtin_nontemporal_load(mbat + (size_t)j * 512 + key);
            }
        }

        // ---- S = Q K^T : 16 rows x 64 keys per wave, K frags from global ----
        f32x4 s[4];
        #pragma unroll
        for (int ct = 0; ct < 4; ++ct) s[ct] = (f32x4){0.f, 0.f, 0.f, 0.f};
        __builtin_amdgcn_s_setprio(1);
        #pragma unroll
        for (int ks = 0; ks < 8; ++ks) {
            #pragma unroll
            for (int ct = 0; ct < 4; ++ct) {
                bf16x8 kf = *reinterpret_cast<const bf16x8*>(
                    kbat + (size_t)(kt * 64 + ct * 16 + lr) * 256 + ks * 32 + lg * 8);
                s[ct] = mfma16(qf[ks], kf, s[ct]);
            }
        }
        __builtin_amdgcn_s_setprio(0);

        // ---- mask + online softmax ----
        float p[4][4];
        #pragma unroll
        for (int ct = 0; ct < 4; ++ct) {
            #pragma unroll
            for (int j = 0; j < 4; ++j)
                p[ct][j] = s[ct][j] * msk[ct][j] - 9.0e15f * (1.0f - msk[ct][j]);
        }
        float scalef[4];
        #pragma unroll
        for (int j = 0; j < 4; ++j) {
            float r0 = fmaxf(fmaxf(p[0][j], p[1][j]), fmaxf(p[2][j], p[3][j]));
            r0 = fmaxf(r0, __shfl_xor(r0, 1));
            r0 = fmaxf(r0, __shfl_xor(r0, 2));
            r0 = fmaxf(r0, __shfl_xor(r0, 4));
            r0 = fmaxf(r0, __shfl_xor(r0, 8));
            float mnew = fmaxf(mreg[j], r0);
            scalef[j] = __expf(mreg[j] - mnew);
            mreg[j] = mnew;
            float psum = 0.f;
            #pragma unroll
            for (int ct = 0; ct < 4; ++ct) {
                float e = __expf(p[ct][j] - mnew);
                p[ct][j] = e;
                psum += e;
            }
            lreg[j] = lreg[j] * scalef[j] + psum;
        }
        #pragma unroll
        for (int ht = 0; ht < 16; ++ht)
            #pragma unroll
            for (int j = 0; j < 4; ++j) acc[ht][j] *= scalef[j];

        // ---- P (D-layout) -> per-wave LDS -> A-fragment layout ----
        #pragma unroll
        for (int ct = 0; ct < 4; ++ct) {
            #pragma unroll
            for (int j = 0; j < 4; ++j) {
                int pr = lg * 4 + j, pc = ct * 16 + lr;
                int byte = (pr * 128 + pc * 2) ^ ((pr & 7) << 4);
                *reinterpret_cast<u16*>(reinterpret_cast<char*>(p_lds[wid]) + byte) = f2bf(p[ct][j]);
            }
        }
        // ---- PV: acc[16 rows][256 h] += P[16][64] @ V[64][256], V from global ----
        #pragma unroll
        for (int ks2 = 0; ks2 < 2; ++ks2) {
            int byteA = (lr * 128 + (ks2 * 32 + lg * 8) * 2) ^ ((lr & 7) << 4);
            bf16x8 pf = *reinterpret_cast<const bf16x8*>(reinterpret_cast<const char*>(p_lds[wid]) + byteA);
            __builtin_amdgcn_s_setprio(1);
            #pragma unroll
            for (int ht = 0; ht < 16; ++ht) {
                bf16x8 vf = *reinterpret_cast<const bf16x8*>(
                    vbat + (size_t)(ht * 16 + lr) * 512 + kt * 64 + ks2 * 32 + lg * 8);
                acc[ht] = mfma16(pf, vf, acc[ht]);
            }
            __builtin_amdgcn_s_setprio(0);
        }
    }

    // finalize: normalize and store bf16
    #pragma unroll
    for (int j = 0; j < 4; ++j) {
        float lt = lreg[j];
        lt += __shfl_xor(lt, 1);
        lt += __shfl_xor(lt, 2);
        lt += __shfl_xor(lt, 4);
        lt += __shfl_xor(lt, 8);
        float inv = 1.0f / lt;
        int qn = n0 + lg * 4 + j;
        u16* orow = Out + ((size_t)b * 512 + qn) * 256;
        #pragma unroll
        for (int ht = 0; ht < 16; ++ht)
            orow[ht * 16 + lr] = f2bf(acc[ht][j] * inv);
    }
}

// ---------------------------------------------------------------------------
// Output projection: Out[65536,256] = relu(A[65536,256](bf16) @ Wo + bo), f32.
// ---------------------------------------------------------------------------
__global__ __launch_bounds__(256, 2) void out_gemm(
    const u16* __restrict__ A, const u16* __restrict__ WOT,
    const float* __restrict__ bO, float* __restrict__ Out)
{
    __shared__ __align__(16) u16 As[128 * 256];
    __shared__ __align__(16) u16 Bs[128 * 64];
    const int tid = threadIdx.x;
    const int m0 = blockIdx.x * 128;

    #pragma unroll
    for (int i = 0; i < 16; ++i) {
        int e = (i * 256 + tid) * 8;
        int r = e >> 8, c = e & 255;
        ushort8 d = *reinterpret_cast<const ushort8*>(A + (size_t)(m0 + r) * 256 + c);
        int byte = (r * 512 + c * 2) ^ ((r & 7) << 4);
        *reinterpret_cast<ushort8*>(reinterpret_cast<char*>(As) + byte) = d;
    }

    const int lane = tid & 63, wid = tid >> 6;
    const int wr = wid >> 1, wc = wid & 1;
    const int lr = lane & 15, lg = lane >> 4;

    for (int cb = 0; cb < 2; ++cb) {
        const int jbase = cb * 128;
        f32x4 acc[4][4];
        #pragma unroll
        for (int a = 0; a < 4; ++a)
            #pragma unroll
            for (int b = 0; b < 4; ++b) acc[a][b] = (f32x4){0.f, 0.f, 0.f, 0.f};

        for (int kk = 0; kk < 256; kk += 64) {
            __syncthreads();
            #pragma unroll
            for (int i = 0; i < 4; ++i) {
                int e = (i * 256 + tid) * 8;
                int r = e >> 6, c = e & 63;
                ushort8 d = *reinterpret_cast<const ushort8*>(WOT + (size_t)(jbase + r) * 256 + kk + c);
                int byte = (r * 128 + c * 2) ^ ((r & 7) << 4);
                *reinterpret_cast<ushort8*>(reinterpret_cast<char*>(Bs) + byte) = d;
            }
            __syncthreads();
            #pragma unroll
            for (int ks = 0; ks < 2; ++ks) {
                bf16x8 af[4], bfr[4];
                #pragma unroll
                for (int mt = 0; mt < 4; ++mt) {
                    int r = wr * 64 + mt * 16 + lr;
                    int byte = (r * 512 + (kk + ks * 32 + lg * 8) * 2) ^ ((r & 7) << 4);
                    af[mt] = *reinterpret_cast<const bf16x8*>(reinterpret_cast<const char*>(As) + byte);
                }
                #pragma unroll
                for (int nt = 0; nt < 4; ++nt) {
                    int r = wc * 64 + nt * 16 + lr;
                    int byte = (r * 128 + (ks * 32 + lg * 8) * 2) ^ ((r & 7) << 4);
                    bfr[nt] = *reinterpret_cast<const bf16x8*>(reinterpret_cast<const char*>(Bs) + byte);
                }
                #pragma unroll
                for (int mt = 0; mt < 4; ++mt)
                    #pragma unroll
                    for (int nt = 0; nt < 4; ++nt)
                        acc[mt][nt] = mfma16(af[mt], bfr[nt], acc[mt][nt]);
            }
        }
        float bcol[4];
        #pragma unroll
        for (int nt = 0; nt < 4; ++nt)
            bcol[nt] = bO[jbase + wc * 64 + nt * 16 + lr];
        #pragma unroll
        for (int mt = 0; mt < 4; ++mt) {
            #pragma unroll
            for (int nt = 0; nt < 4; ++nt) {
                #pragma unroll
                for (int j = 0; j < 4; ++j) {
                    float v = fmaxf(acc[mt][nt][j] + bcol[nt], 0.f);
                    int row = m0 + wr * 64 + mt * 16 + lg * 4 + j;
                    int col = jbase + wc * 64 + nt * 16 + lr;
                    Out[(size_t)row * 256 + col] = v;
                }
            }
        }
    }
}

// ---------------------------------------------------------------------------
extern "C" void kernel_launch(void* const* d_in, const int* in_sizes, int n_in,
                              void* d_out, int out_size, void* d_ws, size_t ws_size,
                              hipStream_t stream) {
    const float* x    = (const float*)d_in[0];
    const float* mask = (const float*)d_in[1];
    const float* Wv   = (const float*)d_in[2];
    const float* bv   = (const float*)d_in[3];
    const float* Wk   = (const float*)d_in[4];
    const float* bk   = (const float*)d_in[5];
    const float* Wq   = (const float*)d_in[6];
    const float* bq   = (const float*)d_in[7];
    const float* Wo   = (const float*)d_in[8];
    const float* bo   = (const float*)d_in[9];
    float* out = (float*)d_out;

    char* ws = (char*)d_ws;
    u16* WT  = (u16*)(ws);                          // 768*256 bf16 = 384KB
    u16* WOT = (u16*)(ws + 393216);                 // 256*256 bf16 = 128KB
    u16* Qb  = (u16*)(ws + 524288);                 // 33.55MB (also attn out)
    u16* Kb  = (u16*)(ws + 524288 + 33554432);      // 33.55MB
    u16* VTb = (u16*)(ws + 524288 + 2 * 33554432);  // 33.55MB, [b][h][n]

    prep_w<<<1024, 256, 0, stream>>>(Wq, Wk, Wv, Wo, WT, WOT);
    qkv_gemm<<<512, 256, 0, stream>>>(x, WT, bq, bk, bv, Qb, Kb, VTb);
    attn_kernel<<<1024, 256, 0, stream>>>(Qb, Kb, VTb, mask, Qb);
    out_gemm<<<512, 256, 0, stream>>>(Qb, WOT, bo, out);
}